// Round 12
// baseline (119.948 us; speedup 1.0000x reference)
//
#include <hip/hip_runtime.h>
#include <hip/hip_fp16.h>
#include <stdint.h>

#define HH   56
#define WW   56
#define HWP  3136
#define CC   256
#define GG   16
#define CGR  16
#define KT   7
#define KK   49
#define TH   2
#define XROW 32            // u32 per sXh row (64 f16)
#define XPL  260           // u32 per sXh ch-plane (8*32+4)

typedef _Float16 h2_t   __attribute__((ext_vector_type(2)));
typedef __fp16   fp16x2 __attribute__((ext_vector_type(2)));
typedef _Float16 v8h    __attribute__((ext_vector_type(8)));
typedef float    v4f    __attribute__((ext_vector_type(4)));
union pk32 { uint32_t u; h2_t h; __half2 hh; fp16x2 f; };
union frag { uint32_t u[4]; v8h h; };

static __device__ __forceinline__ uint32_t pkrtz(float a, float b) {
    pk32 p; p.f = __builtin_amdgcn_cvt_pkrtz(a, b); return p.u;
}

// ---- fold: Wc = sw@rw (f16-packed, [784][128 u32]), bc = sw@rb + sb (f32) ----
// block = 2 rows x 128 col-pairs; grid 392.
__global__ __launch_bounds__(256)
void fold(const float* __restrict__ sw, const float* __restrict__ rw,
          const float* __restrict__ rb, const float* __restrict__ sb,
          uint32_t* __restrict__ wc2, float* __restrict__ bc)
{
    const int t = threadIdx.x;
    const int row = blockIdx.x * 2 + (t >> 7);   // wave-uniform (waves 0-1 / 2-3)
    const int pp  = t & 127;
    const float* swr = sw + (size_t)row * 64;    // wave-uniform row -> s_loads
    float a0 = 0.f, a1 = 0.f;
#pragma unroll
    for (int c = 0; c < 64; ++c) {
        const float s = swr[c];
        const float2 rv = *(const float2*)&rw[(size_t)c * CC + 2 * pp];
        a0 += s * rv.x; a1 += s * rv.y;
    }
    wc2[(size_t)row * 128 + pp] = pkrtz(a0, a1);
    if (pp == 0) {
        float bacc = 0.f;
        for (int c = 0; c < 64; ++c) bacc += swr[c] * rb[c];
        bc[row] = bacc + sb[row];
    }
}

// ---- fully-fused: kern-gen GEMM (Wc@X, K=256) + involution ------------------
// LDS: sXh 16.25 KB + ldsB 2x14.3 KB (sK f16 overlays buf0) = 45 KB -> 3 blocks/CU
__global__ __launch_bounds__(256, 3)
void invol_fused(const float* __restrict__ x, const uint32_t* __restrict__ wc2,
                 const float* __restrict__ bc, float* __restrict__ out)
{
    const int h0 = blockIdx.x * TH, g = blockIdx.y, b = blockIdx.z;

    __shared__ __align__(16) uint32_t sXh[16 * XPL];   // f16 own-group x, [ch][row][64f16]
    __shared__ __align__(16) uint32_t ldsB[2][3584];   // [q4][px][4j]; sK overlays ldsB[0]

    const int t = threadIdx.x;
    const int wave = t >> 6, lane = t & 63, quad = lane >> 4, n16 = lane & 15;

    const float* xb = x + (size_t)b * CC * HWP + h0 * WW;   // strip base (112 px contiguous)

    // A-frags: 8 k-chunks of the wave's 16 Wc rows (L2/L3-hot, wave-uniform block)
    const int mt0 = wave * 16 + n16;
    const int mtap = mt0 > 48 ? 48 : mt0;
    const uint32_t* wr = wc2 + (size_t)(g * KK + mtap) * 128;
    frag af[8];
#pragma unroll
    for (int kc = 0; kc < 8; ++kc)
        *(uint4*)af[kc].u = *(const uint4*)&wr[kc * 16 + quad * 4];

    float bvv[4];
#pragma unroll
    for (int reg = 0; reg < 4; ++reg) {
        const int tp = wave * 16 + quad * 4 + reg;
        bvv[reg] = (tp < KK) ? bc[g * KK + tp] : 0.f;
    }

    // ---- stage chunk 0 (ch 0..63) into ldsB[0], B-frag order ----
#pragma unroll
    for (int k = 0; k < 4; ++k) {
        const int s = t + 256 * k;                     // 896 b128 slots
        if (s < 896) {
            const int q4 = s / 112, px = s % 112;
            const float* xc = xb + (size_t)(q4 * 8) * HWP + px;
            uint4 w;
            w.x = pkrtz(xc[0],          xc[(size_t)1 * HWP]);
            w.y = pkrtz(xc[(size_t)2 * HWP], xc[(size_t)3 * HWP]);
            w.z = pkrtz(xc[(size_t)4 * HWP], xc[(size_t)5 * HWP]);
            w.w = pkrtz(xc[(size_t)6 * HWP], xc[(size_t)7 * HWP]);
            *(uint4*)&ldsB[0][(q4 * 112 + px) * 4] = w;
        }
    }

    // ---- sXh: halo zero + own-group interior (f16) ----
    {
        const int ch = t >> 4, rr = (t >> 1) & 7, side = t & 1;
        uint2 z; z.x = 0; z.y = 0;
        *(uint2*)&sXh[ch * XPL + rr * XROW + (side ? 30 : 0)] = z;
    }
    {
        const float* xg = x + (size_t)(b * CC + g * CGR) * HWP;
#pragma unroll
        for (int k = 0; k < 7; ++k) {
            const int i = t + 256 * k;                 // 1792 exact
            const int w4 = i % 14, rr = (i / 14) % 8, ch = i / 112;
            const int hh = h0 - 3 + rr;
            float4 v = make_float4(0.f, 0.f, 0.f, 0.f);
            if (hh >= 0 && hh < HH)
                v = *(const float4*)&xg[(size_t)ch * HWP + hh * WW + 4 * w4];
            uint2 p; p.x = pkrtz(v.x, v.y); p.y = pkrtz(v.z, v.w);
            *(uint2*)&sXh[ch * XPL + rr * XROW + 2 + 2 * w4] = p;
        }
    }
    __syncthreads();                                   // barrier 1: chunk0 + sXh ready

    // ---- GEMM: K[49][112] = Wc_g[49][256] @ X[256][112]; 4x64-ch chunks, dbuf ----
    v4f acc[7];
#pragma unroll
    for (int nt = 0; nt < 7; ++nt) acc[nt] = v4f{0.f, 0.f, 0.f, 0.f};
#pragma unroll
    for (int kc = 0; kc < 4; ++kc) {
        if (kc < 3) {                                  // stage next chunk into other buf
            uint32_t* buf = ldsB[(kc + 1) & 1];
#pragma unroll
            for (int k = 0; k < 4; ++k) {
                const int s = t + 256 * k;
                if (s < 896) {
                    const int q4 = s / 112, px = s % 112;
                    const float* xc = xb + (size_t)((kc + 1) * 64 + q4 * 8) * HWP + px;
                    uint4 w;
                    w.x = pkrtz(xc[0],          xc[(size_t)1 * HWP]);
                    w.y = pkrtz(xc[(size_t)2 * HWP], xc[(size_t)3 * HWP]);
                    w.z = pkrtz(xc[(size_t)4 * HWP], xc[(size_t)5 * HWP]);
                    w.w = pkrtz(xc[(size_t)6 * HWP], xc[(size_t)7 * HWP]);
                    *(uint4*)&buf[(q4 * 112 + px) * 4] = w;
                }
            }
        }
        const uint32_t* B = ldsB[kc & 1];
#pragma unroll
        for (int nt = 0; nt < 7; ++nt) {
            const int pxm = (nt * 16 + n16) * 4;
            frag b0, b1;
            *(uint4*)b0.u = *(const uint4*)&B[quad * 448 + pxm];
            *(uint4*)b1.u = *(const uint4*)&B[(4 + quad) * 448 + pxm];
            acc[nt] = __builtin_amdgcn_mfma_f32_16x16x32_f16(af[2 * kc].h,     b0.h, acc[nt], 0, 0, 0);
            acc[nt] = __builtin_amdgcn_mfma_f32_16x16x32_f16(af[2 * kc + 1].h, b1.h, acc[nt], 0, 0, 0);
        }
        __syncthreads();                               // barriers 2..5
    }

    // ---- epilogue -> sK f16 [tap][112] (overlays ldsB[0]; buf0 reads done) ----
    {
        _Float16* sK = (_Float16*)ldsB[0];
#pragma unroll
        for (int nt = 0; nt < 7; ++nt) {
            const int px = nt * 16 + n16;
#pragma unroll
            for (int reg = 0; reg < 4; ++reg) {
                const int tp = wave * 16 + quad * 4 + reg;
                if (tp < KK) sK[tp * 112 + px] = (_Float16)(acc[nt][reg] + bvv[reg]);
            }
        }
    }
    __syncthreads();                                   // barrier 6: sK ready

    // ---- phase C (round-9 proven): t<224, thread = (ch, r, wq), 8 px out ----
    if (t < 224) {
        const int ch = t & 15, q = t >> 4, r = q & 1, wq = q >> 1;
        const uint32_t* xpl = &sXh[ch * XPL + 4 * wq];
        const uint32_t* U = ldsB[0];
        float o0=0,o1=0,o2=0,o3=0,o4=0,o5=0,o6=0,o7=0;
#pragma unroll
        for (int kh = 0; kh < KT; ++kh) {
            const int rr = r + kh;
            uint32_t E[8];
            *(uint4*)&E[0] = *(const uint4*)&xpl[rr * XROW];
            *(uint4*)&E[4] = *(const uint4*)&xpl[rr * XROW + 4];
            uint32_t O[7];
#pragma unroll
            for (int j = 0; j < 7; ++j) O[j] = __builtin_amdgcn_alignbit(E[j + 1], E[j], 16);
            pk32 va0, va1, va2, va3;
            va0.u = va1.u = va2.u = va3.u = 0;
            const uint32_t* kq = &U[(kh * KT) * 56 + r * 28 + 4 * wq];
#pragma unroll
            for (int kw = 0; kw < KT; ++kw) {
                const uint4 kk = *(const uint4*)&kq[kw * 56];
                pk32 k0, k1, k2, k3; k0.u = kk.x; k1.u = kk.y; k2.u = kk.z; k3.u = kk.w;
                pk32 s0, s1, s2, s3;
                if (kw & 1) {
                    const int e = (kw + 1) >> 1;
                    s0.u = E[e]; s1.u = E[e + 1]; s2.u = E[e + 2]; s3.u = E[e + 3];
                } else {
                    const int oI = kw >> 1;
                    s0.u = O[oI]; s1.u = O[oI + 1]; s2.u = O[oI + 2]; s3.u = O[oI + 3];
                }
                va0.hh = __hfma2(k0.hh, s0.hh, va0.hh);
                va1.hh = __hfma2(k1.hh, s1.hh, va1.hh);
                va2.hh = __hfma2(k2.hh, s2.hh, va2.hh);
                va3.hh = __hfma2(k3.hh, s3.hh, va3.hh);
            }
            const float2 f0 = __half22float2(va0.hh); o0 += f0.x; o1 += f0.y;
            const float2 f1 = __half22float2(va1.hh); o2 += f1.x; o3 += f1.y;
            const float2 f2 = __half22float2(va2.hh); o4 += f2.x; o5 += f2.y;
            const float2 f3 = __half22float2(va3.hh); o6 += f3.x; o7 += f3.y;
        }
        float* op = out + (size_t)(b * CC + g * CGR + ch) * HWP + (h0 + r) * WW + 8 * wq;
        *(float4*)&op[0] = make_float4(o0, o1, o2, o3);
        *(float4*)&op[4] = make_float4(o4, o5, o6, o7);
    }
}

extern "C" void kernel_launch(void* const* d_in, const int* in_sizes, int n_in,
                              void* d_out, int out_size, void* d_ws, size_t ws_size,
                              hipStream_t stream)
{
    const float* x  = (const float*)d_in[0];   // (4,256,56,56)
    const float* rw = (const float*)d_in[1];   // (64,256)
    const float* rb = (const float*)d_in[2];   // (64,)
    const float* sw = (const float*)d_in[3];   // (784,64)
    const float* sb = (const float*)d_in[4];   // (784,)
    float* out  = (float*)d_out;               // (4,256,56,56)

    uint32_t* wc2 = (uint32_t*)d_ws;           // [784][128] u32 = 401 KB
    float*    bcb = (float*)(wc2 + 784 * 128); // [784] f32

    // composite weight: kern = (sw@rw)@x + (sw@rb + sb)
    fold<<<dim3(392, 1, 1), 256, 0, stream>>>(sw, rw, rb, sb, wc2, bcb);
    // single fused kernel: Wc@X GEMM -> kern in LDS -> involution
    invol_fused<<<dim3(HH / TH, GG, 4), 256, 0, stream>>>(x, wc2, bcb, out);
}

// Round 13
// 95.771 us; speedup vs baseline: 1.2524x; 1.2524x over previous
//
#include <hip/hip_runtime.h>
#include <hip/hip_fp16.h>
#include <stdint.h>

#define HH   56
#define WW   56
#define HWP  3136
#define CC   256
#define GG   16
#define CGR  16
#define KT   7
#define KK   49
#define RCP  32            // packed f16 channel-pairs (64 ch)
#define TH   2
#define XROW 32            // u32 per sXh row (64 f16)
#define XPL  260           // u32 per sXh ch-plane (8*32+4)

typedef _Float16 h2_t   __attribute__((ext_vector_type(2)));
typedef __fp16   fp16x2 __attribute__((ext_vector_type(2)));
typedef _Float16 v8h    __attribute__((ext_vector_type(8)));
typedef float    v4f    __attribute__((ext_vector_type(4)));
union pk32 { uint32_t u; h2_t h; __half2 hh; fp16x2 f; };
union frag { uint32_t u[4]; v8h h; };

static __device__ __forceinline__ uint32_t pkrtz(float a, float b) {
    pk32 p; p.f = __builtin_amdgcn_cvt_pkrtz(a, b); return p.u;
}

// pack a 32-wide f32 k-segment into an 8xf16 MFMA A-half-fragment
static __device__ __forceinline__ frag pack_afrag(const float* rowp, int quad) {
    frag a;
    const float4 p0 = *(const float4*)&rowp[quad * 8];
    const float4 p1 = *(const float4*)&rowp[quad * 8 + 4];
    a.u[0] = pkrtz(p0.x, p0.y); a.u[1] = pkrtz(p0.z, p0.w);
    a.u[2] = pkrtz(p1.x, p1.y); a.u[3] = pkrtz(p1.z, p1.w);
    return a;
}

// ---- gemm1 via MFMA: h2[b][cpair][px] planes; px-tile 32, K=256 prefetched ----
__global__ __launch_bounds__(256)
void gemm1_mfma(const float* __restrict__ rw, const float* __restrict__ rb,
                const float* __restrict__ x, uint32_t* __restrict__ h2)
{
    const int b = blockIdx.z, px0 = blockIdx.x * 32;
    const int t = threadIdx.x;
    const int wave = t >> 6, lane = t & 63, quad = lane >> 4, n16 = lane & 15;

    __shared__ __align__(16) uint32_t ldsB[2][8 * 128];   // [buf][q4*128+px*4+jj], 8 KB

    const int px = t & 31;          // staging: 32 px x 8 q4
    const int q4 = t >> 5;
    const float* xb = x + (size_t)b * CC * HWP + px0 + px;

    // prefetch all 4 K-chunks of B (x) into registers
    float r[4][8];
#pragma unroll
    for (int k = 0; k < 4; ++k)
#pragma unroll
        for (int cc = 0; cc < 8; ++cc)
            r[k][cc] = xb[(size_t)(k * 64 + q4 * 8 + cc) * HWP];

    // pack all 4 K-chunks of A (rw, f32 -> f16) up-front
    const float* rwr = rw + (size_t)(wave * 16 + n16) * CC;
    frag af0[4], af1[4];
#pragma unroll
    for (int k = 0; k < 4; ++k) {
        af0[k] = pack_afrag(rwr + k * 64, quad);
        af1[k] = pack_afrag(rwr + k * 64 + 32, quad);
    }

    {   // stage chunk 0
        uint4 w;
        w.x = pkrtz(r[0][0], r[0][1]); w.y = pkrtz(r[0][2], r[0][3]);
        w.z = pkrtz(r[0][4], r[0][5]); w.w = pkrtz(r[0][6], r[0][7]);
        *(uint4*)&ldsB[0][q4 * 128 + px * 4] = w;
    }
    __syncthreads();

    v4f acc[2];
    acc[0] = v4f{0.f,0.f,0.f,0.f}; acc[1] = v4f{0.f,0.f,0.f,0.f};
#pragma unroll
    for (int k = 0; k < 4; ++k) {
        if (k < 3) {    // stage next chunk into other buffer (register source only)
            uint4 w;
            w.x = pkrtz(r[k+1][0], r[k+1][1]); w.y = pkrtz(r[k+1][2], r[k+1][3]);
            w.z = pkrtz(r[k+1][4], r[k+1][5]); w.w = pkrtz(r[k+1][6], r[k+1][7]);
            *(uint4*)&ldsB[(k + 1) & 1][q4 * 128 + px * 4] = w;
        }
        const uint32_t* B = ldsB[k & 1];
#pragma unroll
        for (int nt = 0; nt < 2; ++nt) {
            frag b0, b1;
            *(uint4*)b0.u = *(const uint4*)&B[quad * 128 + (nt * 16 + n16) * 4];
            *(uint4*)b1.u = *(const uint4*)&B[(4 + quad) * 128 + (nt * 16 + n16) * 4];
            acc[nt] = __builtin_amdgcn_mfma_f32_16x16x32_f16(af0[k].h, b0.h, acc[nt], 0, 0, 0);
            acc[nt] = __builtin_amdgcn_mfma_f32_16x16x32_f16(af1[k].h, b1.h, acc[nt], 0, 0, 0);
        }
        __syncthreads();
    }
    uint32_t* hb = h2 + (size_t)b * RCP * HWP + px0;
#pragma unroll
    for (int nt = 0; nt < 2; ++nt)
#pragma unroll
        for (int pr = 0; pr < 2; ++pr) {
            const int m0 = wave * 16 + quad * 4 + 2 * pr;
            hb[(size_t)(wave * 8 + quad * 2 + pr) * HWP + nt * 16 + n16] =
                pkrtz(acc[nt][2 * pr] + rb[m0], acc[nt][2 * pr + 1] + rb[m0 + 1]);
        }
}

// ---- fused MFMA kern-gen + pk-f16 involution (r9 structure) ----------------
// LDS: sXh 16.25 KB + U 14 KB (ldsB overlaid with sK f16) = 30.3 KB -> 4+ blocks/CU
__global__ __launch_bounds__(256, 4)
void invol_fused(const float* __restrict__ x, const uint32_t* __restrict__ h2,
                 const float* __restrict__ sw, const float* __restrict__ sb,
                 float* __restrict__ out)
{
    const int h0 = blockIdx.x * TH, g = blockIdx.y, b = blockIdx.z;

    __shared__ __align__(16) uint32_t sXh[16 * XPL];      // f16 x, [ch][row][64f16]
    __shared__ __align__(16) uint32_t U[8 * 448];         // ldsB [q4*448+px*4+jj]; later sK f16 [tap*112+px]

    const int t = threadIdx.x;
    const int wave = t >> 6, lane = t & 63, quad = lane >> 4, n16 = lane & 15;

    // A-frags packed from f32 sw (wave-uniform row block, L2/L3-hot)
    const int mt0 = wave * 16 + n16;
    const int mtap = mt0 > 48 ? 48 : mt0;
    const float* swr = sw + (size_t)(g * KK + mtap) * 64;
    const frag a0 = pack_afrag(swr, quad);
    const frag a1 = pack_afrag(swr + 32, quad);

    float bvv[4];
#pragma unroll
    for (int reg = 0; reg < 4; ++reg) {
        const int tp = wave * 16 + quad * 4 + reg;
        bvv[reg] = (tp < KK) ? sb[g * KK + tp] : 0.f;
    }

    // stage h2 -> ldsB in B-frag order (one b128 write per 4-channel gather)
    {
        const uint32_t* hb = h2 + (size_t)b * RCP * HWP + h0 * WW;
#pragma unroll
        for (int k = 0; k < 4; ++k) {
            const int i = t + 256 * k;                  // 896 slots
            if (i < 896) {
                const int px = i % 112, q4 = i / 112;
                uint4 w;
                w.x = hb[(size_t)(q4 * 4 + 0) * HWP + px];
                w.y = hb[(size_t)(q4 * 4 + 1) * HWP + px];
                w.z = hb[(size_t)(q4 * 4 + 2) * HWP + px];
                w.w = hb[(size_t)(q4 * 4 + 3) * HWP + px];
                *(uint4*)&U[q4 * 448 + px * 4] = w;
            }
        }
    }

    // halo zero: f16 cols 0..3 / 60..63 per (ch,row) — one b64 per thread
    {
        const int ch = t >> 4, rr = (t >> 1) & 7, side = t & 1;
        uint2 z; z.x = 0; z.y = 0;
        *(uint2*)&sXh[ch * XPL + rr * XROW + (side ? 30 : 0)] = z;
    }

    // x interior -> f16 (invalid rows write zero)
    {
        const float* xb = x + (size_t)(b * CC + g * CGR) * HWP;
#pragma unroll
        for (int k = 0; k < 7; ++k) {
            const int i = t + 256 * k;                  // 1792 exact
            const int w4 = i % 14, rr = (i / 14) % 8, ch = i / 112;
            const int hh = h0 - 3 + rr;
            float4 v = make_float4(0.f, 0.f, 0.f, 0.f);
            if (hh >= 0 && hh < HH)
                v = *(const float4*)&xb[(size_t)ch * HWP + hh * WW + 4 * w4];
            uint2 p; p.x = pkrtz(v.x, v.y); p.y = pkrtz(v.z, v.w);
            *(uint2*)&sXh[ch * XPL + rr * XROW + 2 + 2 * w4] = p;
        }
    }
    __syncthreads();                                    // barrier 1

    // MFMA: K[49][112] = SW[49][64] @ H[64][112]; B-frag = one b128
    v4f acc[7];
#pragma unroll
    for (int nt = 0; nt < 7; ++nt) acc[nt] = v4f{0.f,0.f,0.f,0.f};
#pragma unroll
    for (int nt = 0; nt < 7; ++nt) {
        const int pxm = (nt * 16 + n16) * 4;
        frag b0, b1;
        *(uint4*)b0.u = *(const uint4*)&U[quad * 448 + pxm];
        *(uint4*)b1.u = *(const uint4*)&U[(4 + quad) * 448 + pxm];
        acc[nt] = __builtin_amdgcn_mfma_f32_16x16x32_f16(a0.h, b0.h, acc[nt], 0, 0, 0);
        acc[nt] = __builtin_amdgcn_mfma_f32_16x16x32_f16(a1.h, b1.h, acc[nt], 0, 0, 0);
    }
    __syncthreads();                                    // barrier 2: ldsB dead

    // epilogue -> sK f16 [tap][112]
    {
        _Float16* sK = (_Float16*)U;
#pragma unroll
        for (int nt = 0; nt < 7; ++nt) {
            const int px = nt * 16 + n16;
#pragma unroll
            for (int reg = 0; reg < 4; ++reg) {
                const int tp = wave * 16 + quad * 4 + reg;
                if (tp < KK) sK[tp * 112 + px] = (_Float16)(acc[nt][reg] + bvv[reg]);
            }
        }
    }
    __syncthreads();                                    // barrier 3

    // phase C (r9-proven): t<224, thread = (ch, r, wq), 8 px outputs
    if (t < 224) {
        const int ch = t & 15, q = t >> 4, r = q & 1, wq = q >> 1;
        const uint32_t* xpl = &sXh[ch * XPL + 4 * wq];
        float o0=0,o1=0,o2=0,o3=0,o4=0,o5=0,o6=0,o7=0;
#pragma unroll
        for (int kh = 0; kh < KT; ++kh) {
            const int rr = r + kh;
            uint32_t E[8];
            *(uint4*)&E[0] = *(const uint4*)&xpl[rr * XROW];
            *(uint4*)&E[4] = *(const uint4*)&xpl[rr * XROW + 4];
            uint32_t O[7];
#pragma unroll
            for (int j = 0; j < 7; ++j) O[j] = __builtin_amdgcn_alignbit(E[j + 1], E[j], 16);
            pk32 va0, va1, va2, va3;
            va0.u = va1.u = va2.u = va3.u = 0;
            const uint32_t* kq = &U[(kh * KT) * 56 + r * 28 + 4 * wq];
#pragma unroll
            for (int kw = 0; kw < KT; ++kw) {
                const uint4 kk = *(const uint4*)&kq[kw * 56];
                pk32 k0, k1, k2, k3; k0.u = kk.x; k1.u = kk.y; k2.u = kk.z; k3.u = kk.w;
                pk32 s0, s1, s2, s3;
                if (kw & 1) {
                    const int e = (kw + 1) >> 1;
                    s0.u = E[e]; s1.u = E[e + 1]; s2.u = E[e + 2]; s3.u = E[e + 3];
                } else {
                    const int oI = kw >> 1;
                    s0.u = O[oI]; s1.u = O[oI + 1]; s2.u = O[oI + 2]; s3.u = O[oI + 3];
                }
                va0.hh = __hfma2(k0.hh, s0.hh, va0.hh);
                va1.hh = __hfma2(k1.hh, s1.hh, va1.hh);
                va2.hh = __hfma2(k2.hh, s2.hh, va2.hh);
                va3.hh = __hfma2(k3.hh, s3.hh, va3.hh);
            }
            const float2 f0 = __half22float2(va0.hh); o0 += f0.x; o1 += f0.y;
            const float2 f1 = __half22float2(va1.hh); o2 += f1.x; o3 += f1.y;
            const float2 f2 = __half22float2(va2.hh); o4 += f2.x; o5 += f2.y;
            const float2 f3 = __half22float2(va3.hh); o6 += f3.x; o7 += f3.y;
        }
        float* op = out + (size_t)(b * CC + g * CGR + ch) * HWP + (h0 + r) * WW + 8 * wq;
        *(float4*)&op[0] = make_float4(o0, o1, o2, o3);
        *(float4*)&op[4] = make_float4(o4, o5, o6, o7);
    }
}

extern "C" void kernel_launch(void* const* d_in, const int* in_sizes, int n_in,
                              void* d_out, int out_size, void* d_ws, size_t ws_size,
                              hipStream_t stream)
{
    const float* x  = (const float*)d_in[0];   // (4,256,56,56)
    const float* rw = (const float*)d_in[1];   // (64,256)
    const float* rb = (const float*)d_in[2];   // (64,)
    const float* sw = (const float*)d_in[3];   // (784,64)
    const float* sb = (const float*)d_in[4];   // (784,)
    float* out  = (float*)d_out;               // (4,256,56,56)

    uint32_t* h2 = (uint32_t*)d_ws;            // (4,32,3136) u32 = 1.6 MB

    gemm1_mfma<<<dim3(HWP / 32, 1, 4), 256, 0, stream>>>(rw, rb, x, h2);
    invol_fused<<<dim3(HH / TH, GG, 4), 256, 0, stream>>>(x, h2, sw, sb, out);
}

// Round 14
// 95.147 us; speedup vs baseline: 1.2606x; 1.0066x over previous
//
#include <hip/hip_runtime.h>
#include <hip/hip_fp16.h>
#include <stdint.h>

#define HH   56
#define WW   56
#define HWP  3136
#define CC   256
#define GG   16
#define CGR  16
#define KT   7
#define KK   49
#define TH   2
#define XROW 32            // u32 per sXh row (64 f16)
#define XPL  260           // u32 per sXh ch-plane (8*32+4)
#define PBLK 512           // u32 per h2s pxblk: [q4(8)][px16(16)][jj(4)]
#define NPB  196           // pxblks per batch (3136/16)

typedef _Float16 h2_t   __attribute__((ext_vector_type(2)));
typedef __fp16   fp16x2 __attribute__((ext_vector_type(2)));
typedef _Float16 v8h    __attribute__((ext_vector_type(8)));
typedef float    v4f    __attribute__((ext_vector_type(4)));
union pk32 { uint32_t u; h2_t h; __half2 hh; fp16x2 f; };
union frag { uint32_t u[4]; v8h h; };

static __device__ __forceinline__ uint32_t pkrtz(float a, float b) {
    pk32 p; p.f = __builtin_amdgcn_cvt_pkrtz(a, b); return p.u;
}

// pack a 32-wide f32 k-segment into an 8xf16 MFMA A-half-fragment
static __device__ __forceinline__ frag pack_afrag(const float* rowp, int quad) {
    frag a;
    const float4 p0 = *(const float4*)&rowp[quad * 8];
    const float4 p1 = *(const float4*)&rowp[quad * 8 + 4];
    a.u[0] = pkrtz(p0.x, p0.y); a.u[1] = pkrtz(p0.z, p0.w);
    a.u[2] = pkrtz(p1.x, p1.y); a.u[3] = pkrtz(p1.z, p1.w);
    return a;
}

// ---- gemm1 via MFMA: h2s in strip-major B-frag layout ----------------------
// h2s[b][pxblk][q4][px16][jj]: invol reads B-fragments directly (no re-staging).
__global__ __launch_bounds__(256)
void gemm1_mfma(const float* __restrict__ rw, const float* __restrict__ rb,
                const float* __restrict__ x, uint32_t* __restrict__ h2s)
{
    const int b = blockIdx.z, px0 = blockIdx.x * 32;
    const int t = threadIdx.x;
    const int wave = t >> 6, lane = t & 63, quad = lane >> 4, n16 = lane & 15;

    __shared__ __align__(16) uint32_t ldsB[2][1024];  // staging; epilogue reuses as 32x33 transpose

    const int px = t & 31;          // staging: 32 px x 8 q4
    const int q4 = t >> 5;
    const float* xb = x + (size_t)b * CC * HWP + px0 + px;

    // prefetch all 4 K-chunks of B (x) into registers
    float r[4][8];
#pragma unroll
    for (int k = 0; k < 4; ++k)
#pragma unroll
        for (int cc = 0; cc < 8; ++cc)
            r[k][cc] = xb[(size_t)(k * 64 + q4 * 8 + cc) * HWP];

    // pack all 4 K-chunks of A (rw, f32 -> f16) up-front
    const float* rwr = rw + (size_t)(wave * 16 + n16) * CC;
    frag af0[4], af1[4];
#pragma unroll
    for (int k = 0; k < 4; ++k) {
        af0[k] = pack_afrag(rwr + k * 64, quad);
        af1[k] = pack_afrag(rwr + k * 64 + 32, quad);
    }

    {   // stage chunk 0
        uint4 w;
        w.x = pkrtz(r[0][0], r[0][1]); w.y = pkrtz(r[0][2], r[0][3]);
        w.z = pkrtz(r[0][4], r[0][5]); w.w = pkrtz(r[0][6], r[0][7]);
        *(uint4*)&ldsB[0][q4 * 128 + px * 4] = w;
    }
    __syncthreads();

    v4f acc[2];
    acc[0] = v4f{0.f,0.f,0.f,0.f}; acc[1] = v4f{0.f,0.f,0.f,0.f};
#pragma unroll
    for (int k = 0; k < 4; ++k) {
        if (k < 3) {    // stage next chunk into other buffer (register source only)
            uint4 w;
            w.x = pkrtz(r[k+1][0], r[k+1][1]); w.y = pkrtz(r[k+1][2], r[k+1][3]);
            w.z = pkrtz(r[k+1][4], r[k+1][5]); w.w = pkrtz(r[k+1][6], r[k+1][7]);
            *(uint4*)&ldsB[(k + 1) & 1][q4 * 128 + px * 4] = w;
        }
        const uint32_t* B = ldsB[k & 1];
#pragma unroll
        for (int nt = 0; nt < 2; ++nt) {
            frag b0, b1;
            *(uint4*)b0.u = *(const uint4*)&B[quad * 128 + (nt * 16 + n16) * 4];
            *(uint4*)b1.u = *(const uint4*)&B[(4 + quad) * 128 + (nt * 16 + n16) * 4];
            acc[nt] = __builtin_amdgcn_mfma_f32_16x16x32_f16(af0[k].h, b0.h, acc[nt], 0, 0, 0);
            acc[nt] = __builtin_amdgcn_mfma_f32_16x16x32_f16(af1[k].h, b1.h, acc[nt], 0, 0, 0);
        }
        __syncthreads();
    }

    // epilogue: transpose c-pairs through LDS, then b128-coalesced strip-major stores
    uint32_t* ldsT = &ldsB[0][0];                    // 32 x 33 u32 (both buffers dead)
#pragma unroll
    for (int nt = 0; nt < 2; ++nt)
#pragma unroll
        for (int pr = 0; pr < 2; ++pr) {
            const int cp = wave * 8 + quad * 2 + pr; // channel-pair 0..31
            ldsT[cp * 33 + nt * 16 + n16] =
                pkrtz(acc[nt][2 * pr] + rb[2 * cp], acc[nt][2 * pr + 1] + rb[2 * cp + 1]);
        }
    __syncthreads();
    {
        const int oq4 = t >> 5, px32 = t & 31;
        uint4 w;
        w.x = ldsT[(oq4 * 4 + 0) * 33 + px32];
        w.y = ldsT[(oq4 * 4 + 1) * 33 + px32];
        w.z = ldsT[(oq4 * 4 + 2) * 33 + px32];
        w.w = ldsT[(oq4 * 4 + 3) * 33 + px32];
        uint32_t* hp = h2s + (size_t)b * NPB * PBLK
                     + (size_t)(blockIdx.x * 2 + (px32 >> 4)) * PBLK
                     + oq4 * 64 + (px32 & 15) * 4;
        *(uint4*)hp = w;
    }
}

// ---- fused kern-gen + involution: B-frags direct from global, ONE barrier ---
// LDS: sXh 16.25 KB + sK 10.97 KB = 27.2 KB -> 5 blocks/CU
__global__ __launch_bounds__(256, 5)
void invol_fused(const float* __restrict__ x, const uint32_t* __restrict__ h2s,
                 const float* __restrict__ sw, const float* __restrict__ sb,
                 float* __restrict__ out)
{
    const int h0 = blockIdx.x * TH, g = blockIdx.y, b = blockIdx.z;

    __shared__ __align__(16) uint32_t sXh[16 * XPL];   // f16 x, [ch][row][64f16]
    __shared__ __align__(16) uint32_t sK[KK * 56];     // kern f16 [tap][112px]

    const int t = threadIdx.x;
    const int wave = t >> 6, lane = t & 63, quad = lane >> 4, n16 = lane & 15;

    // A-frags packed from f32 sw (wave-uniform row block, L2/L3-hot)
    const int mt0 = wave * 16 + n16;
    const int mtap = mt0 > 48 ? 48 : mt0;
    const float* swr = sw + (size_t)(g * KK + mtap) * 64;
    const frag a0 = pack_afrag(swr, quad);
    const frag a1 = pack_afrag(swr + 32, quad);

    float bvv[4];
#pragma unroll
    for (int reg = 0; reg < 4; ++reg) {
        const int tp = wave * 16 + quad * 4 + reg;
        bvv[reg] = (tp < KK) ? sb[g * KK + tp] : 0.f;
    }

    // sXh: halo zero + own-group interior (f16); no barrier needed until phase C
    {
        const int ch = t >> 4, rr = (t >> 1) & 7, side = t & 1;
        uint2 z; z.x = 0; z.y = 0;
        *(uint2*)&sXh[ch * XPL + rr * XROW + (side ? 30 : 0)] = z;
    }
    {
        const float* xb = x + (size_t)(b * CC + g * CGR) * HWP;
#pragma unroll
        for (int k = 0; k < 7; ++k) {
            const int i = t + 256 * k;                  // 1792 exact
            const int w4 = i % 14, rr = (i / 14) % 8, ch = i / 112;
            const int hh = h0 - 3 + rr;
            float4 v = make_float4(0.f, 0.f, 0.f, 0.f);
            if (hh >= 0 && hh < HH)
                v = *(const float4*)&xb[(size_t)ch * HWP + hh * WW + 4 * w4];
            uint2 p; p.x = pkrtz(v.x, v.y); p.y = pkrtz(v.z, v.w);
            *(uint2*)&sXh[ch * XPL + rr * XROW + 2 + 2 * w4] = p;
        }
    }

    // MFMA: K[49][112] = SW[49][64] @ H[64][112]; B-frags straight from global h2s
    {
        const uint32_t* hb = h2s + (size_t)b * NPB * PBLK + (size_t)(blockIdx.x * 7) * PBLK;
        v4f acc[7];
#pragma unroll
        for (int nt = 0; nt < 7; ++nt) acc[nt] = v4f{0.f,0.f,0.f,0.f};
#pragma unroll
        for (int nt = 0; nt < 7; ++nt) {
            const uint32_t* pb = hb + nt * PBLK + n16 * 4;
            frag b0, b1;
            *(uint4*)b0.u = *(const uint4*)&pb[quad * 64];
            *(uint4*)b1.u = *(const uint4*)&pb[(4 + quad) * 64];
            acc[nt] = __builtin_amdgcn_mfma_f32_16x16x32_f16(a0.h, b0.h, acc[nt], 0, 0, 0);
            acc[nt] = __builtin_amdgcn_mfma_f32_16x16x32_f16(a1.h, b1.h, acc[nt], 0, 0, 0);
        }
        // epilogue -> sK f16 [tap][112]
        _Float16* sKh = (_Float16*)sK;
#pragma unroll
        for (int nt = 0; nt < 7; ++nt) {
            const int px = nt * 16 + n16;
#pragma unroll
            for (int reg = 0; reg < 4; ++reg) {
                const int tp = wave * 16 + quad * 4 + reg;
                if (tp < KK) sKh[tp * 112 + px] = (_Float16)(acc[nt][reg] + bvv[reg]);
            }
        }
    }
    __syncthreads();                                    // the ONE barrier

    // phase C: t<224, thread = (ch, r, wq), 8 px outputs
    if (t < 224) {
        const int ch = t & 15, q = t >> 4, r = q & 1, wq = q >> 1;
        const uint32_t* xpl = &sXh[ch * XPL + 4 * wq];
        float o0=0,o1=0,o2=0,o3=0,o4=0,o5=0,o6=0,o7=0;
#pragma unroll
        for (int kh = 0; kh < KT; ++kh) {
            const int rr = r + kh;
            uint32_t E[8];
            *(uint4*)&E[0] = *(const uint4*)&xpl[rr * XROW];
            *(uint4*)&E[4] = *(const uint4*)&xpl[rr * XROW + 4];
            uint32_t O[7];
#pragma unroll
            for (int j = 0; j < 7; ++j) O[j] = __builtin_amdgcn_alignbit(E[j + 1], E[j], 16);
            pk32 va0, va1, va2, va3;
            va0.u = va1.u = va2.u = va3.u = 0;
            const uint32_t* kq = &sK[(kh * KT) * 56 + r * 28 + 4 * wq];
#pragma unroll
            for (int kw = 0; kw < KT; ++kw) {
                const uint4 kk = *(const uint4*)&kq[kw * 56];
                pk32 k0, k1, k2, k3; k0.u = kk.x; k1.u = kk.y; k2.u = kk.z; k3.u = kk.w;
                pk32 s0, s1, s2, s3;
                if (kw & 1) {
                    const int e = (kw + 1) >> 1;
                    s0.u = E[e]; s1.u = E[e + 1]; s2.u = E[e + 2]; s3.u = E[e + 3];
                } else {
                    const int oI = kw >> 1;
                    s0.u = O[oI]; s1.u = O[oI + 1]; s2.u = O[oI + 2]; s3.u = O[oI + 3];
                }
                va0.hh = __hfma2(k0.hh, s0.hh, va0.hh);
                va1.hh = __hfma2(k1.hh, s1.hh, va1.hh);
                va2.hh = __hfma2(k2.hh, s2.hh, va2.hh);
                va3.hh = __hfma2(k3.hh, s3.hh, va3.hh);
            }
            const float2 f0 = __half22float2(va0.hh); o0 += f0.x; o1 += f0.y;
            const float2 f1 = __half22float2(va1.hh); o2 += f1.x; o3 += f1.y;
            const float2 f2 = __half22float2(va2.hh); o4 += f2.x; o5 += f2.y;
            const float2 f3 = __half22float2(va3.hh); o6 += f3.x; o7 += f3.y;
        }
        float* op = out + (size_t)(b * CC + g * CGR + ch) * HWP + (h0 + r) * WW + 8 * wq;
        *(float4*)&op[0] = make_float4(o0, o1, o2, o3);
        *(float4*)&op[4] = make_float4(o4, o5, o6, o7);
    }
}

extern "C" void kernel_launch(void* const* d_in, const int* in_sizes, int n_in,
                              void* d_out, int out_size, void* d_ws, size_t ws_size,
                              hipStream_t stream)
{
    const float* x  = (const float*)d_in[0];   // (4,256,56,56)
    const float* rw = (const float*)d_in[1];   // (64,256)
    const float* rb = (const float*)d_in[2];   // (64,)
    const float* sw = (const float*)d_in[3];   // (784,64)
    const float* sb = (const float*)d_in[4];   // (784,)
    float* out  = (float*)d_out;               // (4,256,56,56)

    uint32_t* h2s = (uint32_t*)d_ws;           // [4][196][512] u32 = 1.6 MB, B-frag order

    gemm1_mfma<<<dim3(HWP / 32, 1, 4), 256, 0, stream>>>(rw, rb, x, h2s);
    invol_fused<<<dim3(HH / TH, GG, 4), 256, 0, stream>>>(x, h2s, sw, sb, out);
}